// Round 1
// baseline (404.315 us; speedup 1.0000x reference)
//
#include <hip/hip_runtime.h>

#define SEQ 288
#define INP 7
#define HID 128
#define TLEN 288
#define OUTD 3

typedef _Float16 f16x8 __attribute__((ext_vector_type(8)));
typedef float f32x4 __attribute__((ext_vector_type(4)));

__device__ __forceinline__ float fast_sigmoid(float x) {
    float e = __expf(-x);
    return __builtin_amdgcn_rcpf(1.0f + e);
}
__device__ __forceinline__ float fast_tanh(float x) {
    float e = __expf(-2.0f * x);
    return 2.0f * __builtin_amdgcn_rcpf(1.0f + e) - 1.0f;
}

// Pull D-frag value for (batch=bb, unitcol=col) into this lane.
// D layout (m89-verified): col=lane&15, row=(lane>>4)*4+reg. Valid batch rows
// 0..3 live in lanes 0..15, reg=batch. Source lane = col, reg = bb.
__device__ __forceinline__ float redist(f32x4 a, int col, int bb) {
    float t0 = __shfl(a[0], col);
    float t1 = __shfl(a[1], col);
    float t2 = __shfl(a[2], col);
    float t3 = __shfl(a[3], col);
    float lo = (bb & 1) ? t1 : t0;
    float hi = (bb & 1) ? t3 : t2;
    return (bb & 2) ? hi : lo;
}

__global__ __launch_bounds__(512, 2)
void enc_dec_kernel(const float* __restrict__ x,
                    const float* __restrict__ eWih, const float* __restrict__ eWhh,
                    const float* __restrict__ ebih, const float* __restrict__ ebhh,
                    const float* __restrict__ dWih, const float* __restrict__ dWhh,
                    const float* __restrict__ dbih, const float* __restrict__ dbhh,
                    const float* __restrict__ oW,  const float* __restrict__ ob,
                    float* __restrict__ out)
{
    // h buffer in A-fragment layout: [dbuf][kc(5)][Arow=batch(16)][ke(32)] f16.
    // kc=4 is the folded x_t slice (ke 0..6 = x, rest stays 0).
    __shared__ __align__(16) _Float16 hbuf[2][5][16][32];
    __shared__ float xl[4][SEQ * INP];     // this block's 4 batch rows of x
    __shared__ float ylds[4][4];           // decoder y feedback (3 used)
    __shared__ float plds[8][4][3];        // per-wave output-projection partials

    const int tid  = threadIdx.x;
    const int wave = tid >> 6;
    const int lane = tid & 63;
    const int col  = lane & 15;    // MFMA m/n-col index
    const int grp  = lane >> 4;    // k-chunk index (0..3)
    const int u    = wave * 16 + col;  // this lane's hidden unit 0..127 (post-redist)
    const int bb   = grp;              // this lane's batch row 0..3 (post-redist)
    const int b0   = blockIdx.x * 4;

    // ---- prologue: zero hbuf, stage x ----
    {
        _Float16* hb = &hbuf[0][0][0][0];
        for (int i = tid; i < 2 * 5 * 16 * 32; i += 512) hb[i] = (_Float16)0.f;
    }
    for (int i = tid; i < 4 * SEQ * INP; i += 512) {
        int b = i / (SEQ * INP), r = i % (SEQ * INP);
        xl[b][r] = x[(size_t)(b0 + b) * (SEQ * INP) + r];
    }

    // ---- encoder weights as persistent B-fragments ----
    // B[k][n]: n = lane&15 -> W row = gt*128 + wave*16 + col; k = kc*32 + grp*8 + e
    f16x8 wfrag[4][5];
    #pragma unroll
    for (int gt = 0; gt < 4; ++gt) {
        const int row = gt * HID + u;
        #pragma unroll
        for (int kc = 0; kc < 4; ++kc) {
            const float* wr = eWhh + (size_t)row * HID + kc * 32 + grp * 8;
            f16x8 wf;
            #pragma unroll
            for (int e = 0; e < 8; ++e) wf[e] = (_Float16)wr[e];
            wfrag[gt][kc] = wf;
        }
        {   // kc=4: Wih columns (j = grp*8+e < 7), else 0
            f16x8 wf;
            #pragma unroll
            for (int e = 0; e < 8; ++e) {
                int j = grp * 8 + e;
                wf[e] = (_Float16)((j < INP) ? eWih[(size_t)row * INP + j] : 0.f);
            }
            wfrag[gt][4] = wf;
        }
    }
    float bias[4];
    #pragma unroll
    for (int gt = 0; gt < 4; ++gt)
        bias[gt] = ebih[gt * HID + u] + ebhh[gt * HID + u];

    __syncthreads();   // xl ready
    if (tid < 4 * INP) {
        int b = tid / INP, j = tid % INP;
        hbuf[0][4][b][j] = (_Float16)xl[b][j];   // x_0
    }
    __syncthreads();   // hbuf[0] ready (h0 = 0)

    float c = 0.f;
    // ---------------- encoder: 288 steps ----------------
    for (int t = 0; t < SEQ; ++t) {
        const int cur = t & 1, nxt = cur ^ 1;
        f16x8 af[5];
        #pragma unroll
        for (int kc = 0; kc < 5; ++kc)
            af[kc] = *(const f16x8*)&hbuf[cur][kc][col][grp * 8];
        f32x4 acc[4];
        #pragma unroll
        for (int gt = 0; gt < 4; ++gt) acc[gt] = (f32x4){0.f, 0.f, 0.f, 0.f};
        #pragma unroll
        for (int kc = 0; kc < 5; ++kc) {
            #pragma unroll
            for (int gt = 0; gt < 4; ++gt)
                acc[gt] = __builtin_amdgcn_mfma_f32_16x16x32_f16(
                              af[kc], wfrag[gt][kc], acc[gt], 0, 0, 0);
        }
        float zi = redist(acc[0], col, bb) + bias[0];
        float zf = redist(acc[1], col, bb) + bias[1];
        float zg = redist(acc[2], col, bb) + bias[2];
        float zo = redist(acc[3], col, bb) + bias[3];
        float si = fast_sigmoid(zi);
        float sf = fast_sigmoid(zf);
        float tg = fast_tanh(zg);
        float so = fast_sigmoid(zo);
        c = sf * c + si * tg;
        float h = so * fast_tanh(c);
        hbuf[nxt][u >> 5][bb][u & 31] = (_Float16)h;
        if (t + 1 < SEQ && tid < 4 * INP) {
            int b = tid / INP, j = tid % INP;
            hbuf[nxt][4][b][j] = (_Float16)xl[b][(t + 1) * INP + j];
        }
        __syncthreads();
    }
    // final h_enc is in hbuf[0] (t=287: nxt=0); c_enc is in-lane.

    // ---------------- decoder prologue ----------------
    #pragma unroll
    for (int gt = 0; gt < 4; ++gt) {       // reload fragments with dec_Whh
        const int row = gt * HID + u;
        #pragma unroll
        for (int kc = 0; kc < 4; ++kc) {
            const float* wr = dWhh + (size_t)row * HID + kc * 32 + grp * 8;
            f16x8 wf;
            #pragma unroll
            for (int e = 0; e < 8; ++e) wf[e] = (_Float16)wr[e];
            wfrag[gt][kc] = wf;
        }
    }
    float bdec[4], Wd[4][3];
    #pragma unroll
    for (int gt = 0; gt < 4; ++gt) {
        bdec[gt] = dbih[gt * HID + u] + dbhh[gt * HID + u];
        #pragma unroll
        for (int j = 0; j < 3; ++j)
            Wd[gt][j] = dWih[(size_t)(gt * HID + u) * 3 + j];
    }
    const float ow0 = oW[u], ow1 = oW[HID + u], ow2 = oW[2 * HID + u];
    const float obv = (tid < 12) ? ob[tid % 3] : 0.f;

    // zbase = dec_Whh @ h_enc + b_dec  (K-slices 0..3 only; y-slice done per-step)
    float zb[4];
    {
        f16x8 af[4];
        #pragma unroll
        for (int kc = 0; kc < 4; ++kc)
            af[kc] = *(const f16x8*)&hbuf[0][kc][col][grp * 8];
        f32x4 acc[4];
        #pragma unroll
        for (int gt = 0; gt < 4; ++gt) acc[gt] = (f32x4){0.f, 0.f, 0.f, 0.f};
        #pragma unroll
        for (int kc = 0; kc < 4; ++kc) {
            #pragma unroll
            for (int gt = 0; gt < 4; ++gt)
                acc[gt] = __builtin_amdgcn_mfma_f32_16x16x32_f16(
                              af[kc], wfrag[gt][kc], acc[gt], 0, 0, 0);
        }
        #pragma unroll
        for (int gt = 0; gt < 4; ++gt)
            zb[gt] = redist(acc[gt], col, bb) + bdec[gt];
    }

    if (tid < 16) ylds[tid >> 2][tid & 3] = 0.f;   // y0 = 0
    __syncthreads();

    const float c_enc = c;
    float* outp = out + (size_t)b0 * (TLEN * OUTD);

    // ---------------- decoder: 288 steps ----------------
    for (int t = 0; t < TLEN; ++t) {
        const float y0 = ylds[bb][0], y1 = ylds[bb][1], y2 = ylds[bb][2];
        float zi = zb[0] + Wd[0][0] * y0 + Wd[0][1] * y1 + Wd[0][2] * y2;
        float zf = zb[1] + Wd[1][0] * y0 + Wd[1][1] * y1 + Wd[1][2] * y2;
        float zg = zb[2] + Wd[2][0] * y0 + Wd[2][1] * y1 + Wd[2][2] * y2;
        float zo = zb[3] + Wd[3][0] * y0 + Wd[3][1] * y1 + Wd[3][2] * y2;
        float si = fast_sigmoid(zi);
        float sf = fast_sigmoid(zf);
        float tg = fast_tanh(zg);
        float so = fast_sigmoid(zo);
        float cd = sf * c_enc + si * tg;
        float hd = so * fast_tanh(cd);
        // output projection partials: sum over this wave's 16 units
        float p0 = ow0 * hd, p1 = ow1 * hd, p2 = ow2 * hd;
        #pragma unroll
        for (int m = 1; m < 16; m <<= 1) {
            p0 += __shfl_xor(p0, m);
            p1 += __shfl_xor(p1, m);
            p2 += __shfl_xor(p2, m);
        }
        if (col == 0) {
            plds[wave][bb][0] = p0;
            plds[wave][bb][1] = p1;
            plds[wave][bb][2] = p2;
        }
        __syncthreads();
        if (tid < 12) {
            int b = tid / 3, q = tid % 3;
            float s = obv;
            #pragma unroll
            for (int w = 0; w < 8; ++w) s += plds[w][b][q];
            outp[(size_t)b * (TLEN * OUTD) + t * OUTD + q] = s;
            ylds[b][q] = s;
        }
        __syncthreads();
    }
}

extern "C" void kernel_launch(void* const* d_in, const int* in_sizes, int n_in,
                              void* d_out, int out_size, void* d_ws, size_t ws_size,
                              hipStream_t stream) {
    (void)in_sizes; (void)n_in; (void)d_ws; (void)ws_size; (void)out_size;
    enc_dec_kernel<<<256, 512, 0, stream>>>(
        (const float*)d_in[0],
        (const float*)d_in[1], (const float*)d_in[2],
        (const float*)d_in[3], (const float*)d_in[4],
        (const float*)d_in[5], (const float*)d_in[6],
        (const float*)d_in[7], (const float*)d_in[8],
        (const float*)d_in[9], (const float*)d_in[10],
        (float*)d_out);
}

// Round 2
// 367.177 us; speedup vs baseline: 1.1011x; 1.1011x over previous
//
#include <hip/hip_runtime.h>

#define SEQ 288
#define INP 7
#define HID 128
#define TLEN 288
#define OUTD 3

typedef _Float16 f16x8 __attribute__((ext_vector_type(8)));
typedef float f32x4 __attribute__((ext_vector_type(4)));

__device__ __forceinline__ float fast_sigmoid(float x) {
    float e = __expf(-x);
    return __builtin_amdgcn_rcpf(1.0f + e);
}
__device__ __forceinline__ float fast_tanh(float x) {
    float e = __expf(-2.0f * x);
    return 2.0f * __builtin_amdgcn_rcpf(1.0f + e) - 1.0f;
}

// Pull D-frag value for (batch=bb, unitcol=col) into this lane.
// D layout (m89): col=lane&15, row=(lane>>4)*4+reg. Valid batch rows 0..3
// live in lanes 0..15 (reg = batch). Source lane = col, reg = bb.
__device__ __forceinline__ float redist(f32x4 a, int col, int bb) {
    float t0 = __shfl(a[0], col);
    float t1 = __shfl(a[1], col);
    float t2 = __shfl(a[2], col);
    float t3 = __shfl(a[3], col);
    float lo = (bb & 1) ? t1 : t0;
    float hi = (bb & 1) ? t3 : t2;
    return (bb & 2) ? hi : lo;
}

__global__ __launch_bounds__(512, 2)
void enc_dec_kernel(const float* __restrict__ x,
                    const float* __restrict__ eWih, const float* __restrict__ eWhh,
                    const float* __restrict__ ebih, const float* __restrict__ ebhh,
                    const float* __restrict__ dWih, const float* __restrict__ dWhh,
                    const float* __restrict__ dbih, const float* __restrict__ dbhh,
                    const float* __restrict__ oW,  const float* __restrict__ ob,
                    float* __restrict__ out)
{
    // h buffer in A-fragment layout, inner dim padded 32->40 f16 (80B rows,
    // 16B-aligned, banks (col*20+grp*4)%32 -> 2-way = free).
    // kc=4 is the folded x_t slice (ke 0..6 = x, rest stays 0).
    __shared__ __align__(16) _Float16 hbuf[2][5][16][40];
    __shared__ float xl[4][SEQ * INP];   // this block's 4 batch rows of x
    __shared__ float zbl[4][4][HID];     // decoder zbase staging [gate][b][u]
    __shared__ float cl[4][HID];         // c_enc staging [b][u]

    const int tid  = threadIdx.x;
    const int wave = tid >> 6;
    const int lane = tid & 63;
    const int col  = lane & 15;        // MFMA m/n-col index
    const int grp  = lane >> 4;        // k-chunk index (0..3)
    const int u    = wave * 16 + col;  // this lane's hidden unit (post-redist)
    const int bb   = grp;              // this lane's batch row (post-redist)
    const int b0   = blockIdx.x * 4;

    // ---- prologue: zero hbuf, stage x ----
    {
        _Float16* hb = &hbuf[0][0][0][0];
        for (int i = tid; i < 2 * 5 * 16 * 40; i += 512) hb[i] = (_Float16)0.f;
    }
    for (int i = tid; i < 4 * SEQ * INP; i += 512) {
        int b = i / (SEQ * INP), r = i % (SEQ * INP);
        xl[b][r] = x[(size_t)(b0 + b) * (SEQ * INP) + r];
    }

    // ---- encoder weights as persistent B-fragments ----
    // B[k][n]: n -> W row = gt*128 + u; k = kc*32 + grp*8 + e
    f16x8 wfrag[4][5];
    #pragma unroll
    for (int gt = 0; gt < 4; ++gt) {
        const int row = gt * HID + u;
        #pragma unroll
        for (int kc = 0; kc < 4; ++kc) {
            const float* wr = eWhh + (size_t)row * HID + kc * 32 + grp * 8;
            f16x8 wf;
            #pragma unroll
            for (int e = 0; e < 8; ++e) wf[e] = (_Float16)wr[e];
            wfrag[gt][kc] = wf;
        }
        {   // kc=4: Wih columns (j = grp*8+e < 7), else 0
            f16x8 wf;
            #pragma unroll
            for (int e = 0; e < 8; ++e) {
                int j = grp * 8 + e;
                wf[e] = (_Float16)((j < INP) ? eWih[(size_t)row * INP + j] : 0.f);
            }
            wfrag[gt][4] = wf;
        }
    }
    float bias[4];
    #pragma unroll
    for (int gt = 0; gt < 4; ++gt)
        bias[gt] = ebih[gt * HID + u] + ebhh[gt * HID + u];

    __syncthreads();   // xl ready
    if (tid < 4 * INP) {
        int b = tid / INP, j = tid % INP;
        hbuf[0][4][b][j] = (_Float16)xl[b][j];   // x_0
    }
    __syncthreads();   // hbuf[0] ready (h0 = 0)

    float c = 0.f;
    // ---------------- encoder: 288 steps ----------------
    for (int t = 0; t < SEQ; ++t) {
        const int cur = t & 1, nxt = cur ^ 1;
        f16x8 af[5];
        #pragma unroll
        for (int kc = 0; kc < 5; ++kc)
            af[kc] = *(const f16x8*)&hbuf[cur][kc][col][grp * 8];
        f32x4 acc[4];
        #pragma unroll
        for (int gt = 0; gt < 4; ++gt)
            acc[gt] = (f32x4){bias[gt], bias[gt], bias[gt], bias[gt]};
        #pragma unroll
        for (int kc = 0; kc < 5; ++kc) {
            #pragma unroll
            for (int gt = 0; gt < 4; ++gt)
                acc[gt] = __builtin_amdgcn_mfma_f32_16x16x32_f16(
                              af[kc], wfrag[gt][kc], acc[gt], 0, 0, 0);
        }
        float zi = redist(acc[0], col, bb);
        float zf = redist(acc[1], col, bb);
        float zg = redist(acc[2], col, bb);
        float zo = redist(acc[3], col, bb);
        float si = fast_sigmoid(zi);
        float sf = fast_sigmoid(zf);
        float tg = fast_tanh(zg);
        float so = fast_sigmoid(zo);
        c = sf * c + si * tg;
        float h = so * fast_tanh(c);
        hbuf[nxt][u >> 5][bb][u & 31] = (_Float16)h;
        if (t + 1 < SEQ && tid < 4 * INP) {
            int b = tid / INP, j = tid % INP;
            hbuf[nxt][4][b][j] = (_Float16)xl[b][(t + 1) * INP + j];
        }
        __syncthreads();
    }
    // final h_enc is in hbuf[0] (t=287: nxt=0); c_enc is in-lane.

    // ---------------- decoder zbase (all 8 waves) ----------------
    #pragma unroll
    for (int gt = 0; gt < 4; ++gt) {       // reload fragments with dec_Whh
        const int row = gt * HID + u;
        #pragma unroll
        for (int kc = 0; kc < 4; ++kc) {
            const float* wr = dWhh + (size_t)row * HID + kc * 32 + grp * 8;
            f16x8 wf;
            #pragma unroll
            for (int e = 0; e < 8; ++e) wf[e] = (_Float16)wr[e];
            wfrag[gt][kc] = wf;
        }
    }
    {
        f16x8 af[4];
        #pragma unroll
        for (int kc = 0; kc < 4; ++kc)
            af[kc] = *(const f16x8*)&hbuf[0][kc][col][grp * 8];
        f32x4 acc[4];
        #pragma unroll
        for (int gt = 0; gt < 4; ++gt) {
            float bd = dbih[gt * HID + u] + dbhh[gt * HID + u];
            acc[gt] = (f32x4){bd, bd, bd, bd};
        }
        #pragma unroll
        for (int kc = 0; kc < 4; ++kc) {
            #pragma unroll
            for (int gt = 0; gt < 4; ++gt)
                acc[gt] = __builtin_amdgcn_mfma_f32_16x16x32_f16(
                              af[kc], wfrag[gt][kc], acc[gt], 0, 0, 0);
        }
        #pragma unroll
        for (int gt = 0; gt < 4; ++gt)
            zbl[gt][bb][u] = redist(acc[gt], col, bb);
        cl[bb][u] = c;
    }
    __syncthreads();

    // ---------------- decoder: 1 wave per batch row, no barriers ----------
    if (wave >= 4) return;
    {
        const int b = wave;
        const int u0 = lane, u1 = 64 + lane;
        float zb0[4], zb1[4], wd0[4][3], wd1[4][3];
        #pragma unroll
        for (int gt = 0; gt < 4; ++gt) {
            zb0[gt] = zbl[gt][b][u0];
            zb1[gt] = zbl[gt][b][u1];
            #pragma unroll
            for (int j = 0; j < 3; ++j) {
                wd0[gt][j] = dWih[(size_t)(gt * HID + u0) * 3 + j];
                wd1[gt][j] = dWih[(size_t)(gt * HID + u1) * 3 + j];
            }
        }
        const float c0 = cl[b][u0], c1 = cl[b][u1];
        float ow0[3], ow1[3];
        #pragma unroll
        for (int j = 0; j < 3; ++j) {
            ow0[j] = oW[j * HID + u0];
            ow1[j] = oW[j * HID + u1];
        }
        const float ob0 = ob[0], ob1 = ob[1], ob2 = ob[2];

        float y0 = 0.f, y1 = 0.f, y2 = 0.f;
        float* orow = out + (size_t)(b0 + b) * (TLEN * OUTD);

        for (int t = 0; t < TLEN; ++t) {
            float z0[4], z1[4];
            #pragma unroll
            for (int gt = 0; gt < 4; ++gt) {
                z0[gt] = zb0[gt] + wd0[gt][0] * y0 + wd0[gt][1] * y1 + wd0[gt][2] * y2;
                z1[gt] = zb1[gt] + wd1[gt][0] * y0 + wd1[gt][1] * y1 + wd1[gt][2] * y2;
            }
            float si0 = fast_sigmoid(z0[0]), sf0 = fast_sigmoid(z0[1]);
            float tg0 = fast_tanh(z0[2]),    so0 = fast_sigmoid(z0[3]);
            float si1 = fast_sigmoid(z1[0]), sf1 = fast_sigmoid(z1[1]);
            float tg1 = fast_tanh(z1[2]),    so1 = fast_sigmoid(z1[3]);
            float cd0 = sf0 * c0 + si0 * tg0;
            float cd1 = sf1 * c1 + si1 * tg1;
            float hd0 = so0 * fast_tanh(cd0);
            float hd1 = so1 * fast_tanh(cd1);
            float p0 = ow0[0] * hd0 + ow1[0] * hd1;
            float p1 = ow0[1] * hd0 + ow1[1] * hd1;
            float p2 = ow0[2] * hd0 + ow1[2] * hd1;
            #pragma unroll
            for (int m = 1; m < 64; m <<= 1) {
                p0 += __shfl_xor(p0, m);
                p1 += __shfl_xor(p1, m);
                p2 += __shfl_xor(p2, m);
            }
            y0 = p0 + ob0;
            y1 = p1 + ob1;
            y2 = p2 + ob2;
            if (lane < 3)
                orow[t * OUTD + lane] = (lane == 0) ? y0 : (lane == 1) ? y1 : y2;
        }
    }
}

extern "C" void kernel_launch(void* const* d_in, const int* in_sizes, int n_in,
                              void* d_out, int out_size, void* d_ws, size_t ws_size,
                              hipStream_t stream) {
    (void)in_sizes; (void)n_in; (void)d_ws; (void)ws_size; (void)out_size;
    enc_dec_kernel<<<256, 512, 0, stream>>>(
        (const float*)d_in[0],
        (const float*)d_in[1], (const float*)d_in[2],
        (const float*)d_in[3], (const float*)d_in[4],
        (const float*)d_in[5], (const float*)d_in[6],
        (const float*)d_in[7], (const float*)d_in[8],
        (const float*)d_in[9], (const float*)d_in[10],
        (float*)d_out);
}